// Round 3
// baseline (220.751 us; speedup 1.0000x reference)
//
#include <hip/hip_runtime.h>
#include <hip/hip_bf16.h>

// Problem constants (from reference setup_inputs)
#define BB 16        // batch
#define TT 288       // time steps
#define NN 4096      // nodes
#define FF 2         // features (only feature 0 used)
#define RR 16        // regions
#define HH 10        // horizon
#define TC 8         // time chunks for phase-1 parallelism
#define TSTEP (TT / TC)   // 36
#define NBLK2 64          // k_pred block count
#define NULLV (-1.0f)

// ---------------------------------------------------------------------------
// Kernel 1: grid (NN/512, TC, BB) = (8,8,16) = 1024 blocks, 256 threads.
// Each thread owns 2 consecutive nodes via float4 loads (one float4 =
// {n0.f0, n0.f1, n1.f0, n1.f1}).  Writes a packed per-(tc,b,n-pair) partial
// {sum0, cnt0, sum1, cnt1} (counts <= 36, exact in fp32) and a per-block
// total (bsum/bcnt) for the global imputation mean.  Block (0,0,0) also
// zero-inits the regional accumulators + the k_pred completion counter
// (stream order guarantees visibility to k_pred).
// ---------------------------------------------------------------------------
__global__ __launch_bounds__(256) void k_partial(
    const float4* __restrict__ x4,
    float4* __restrict__ ps4,
    float* __restrict__ bsum, unsigned int* __restrict__ bcnt,
    float* __restrict__ regsum, unsigned int* __restrict__ counter) {
  const int tid = threadIdx.x;
  const int n0  = blockIdx.x * 512 + tid * 2;
  const int tc  = blockIdx.y;
  const int b   = blockIdx.z;

  if (blockIdx.x == 0 && tc == 0 && b == 0) {
    regsum[tid] = 0.0f;                 // BB*RR = 256 accumulators
    if (tid == 0) *counter = 0u;
  }

  const float4* p = x4 + ((size_t)(b * TT + tc * TSTEP) * NN + n0) / 2;
  float s0 = 0.0f, s1 = 0.0f;
  unsigned int c0 = 0, c1 = 0;
#pragma unroll 12
  for (int t = 0; t < TSTEP; ++t) {
    float4 v = p[(size_t)t * (NN / 2)];
    bool v0 = (v.x != NULLV);
    bool v1 = (v.z != NULLV);
    s0 += v0 ? v.x : 0.0f;  c0 += v0 ? 1u : 0u;
    s1 += v1 ? v.z : 0.0f;  c1 += v1 ? 1u : 0u;
  }
  ps4[(((size_t)tc * BB + b) * NN + n0) / 2] =
      make_float4(s0, (float)c0, s1, (float)c1);

  // block total -> bsum/bcnt[blockLinear]  (plain store, no atomics)
  float rs = s0 + s1;
  unsigned int rc = c0 + c1;
  for (int off = 32; off > 0; off >>= 1) {
    rs += __shfl_down(rs, off);
    rc += __shfl_down(rc, off);
  }
  __shared__ float sh_s[4];
  __shared__ unsigned int sh_c[4];
  const int wid = tid >> 6;
  if ((tid & 63) == 0) { sh_s[wid] = rs; sh_c[wid] = rc; }
  __syncthreads();
  if (tid == 0) {
    const int blk = (blockIdx.z * TC + blockIdx.y) * 8 + blockIdx.x;
    bsum[blk] = sh_s[0] + sh_s[1] + sh_s[2] + sh_s[3];
    bcnt[blk] = sh_c[0] + sh_c[1] + sh_c[2] + sh_c[3];
  }
}

// ---------------------------------------------------------------------------
// Kernel 2: 64 blocks x 256 threads; each thread owns 4 consecutive nodes.
// (a) every block re-reduces the 1024-entry bsum/bcnt (8 KB, L2-hot) for the
//     global imputation mean; (b) combines TC packed partials, imputes,
//     writes the horizon-tiled [B,H,N] prediction with float4 stores;
// (c) LDS region histogram -> 16 device-scope atomicAdds into regsum;
// (d) LAST block (device-scope counter) computes the region node-histogram
//     and writes the tiled [B,H,R] regional output — fuses old k_final.
// ---------------------------------------------------------------------------
__global__ __launch_bounds__(256) void k_pred(
    const float4* __restrict__ ps4,
    const float4* __restrict__ bsum4, const uint4* __restrict__ bcnt4,
    const int4* __restrict__ cluster4, const int* __restrict__ cluster,
    float4* __restrict__ out4, float* __restrict__ out2,
    float* __restrict__ regsum, unsigned int* __restrict__ counter) {
  const int tid = threadIdx.x;
  const int blk = blockIdx.x;          // 64 blocks
  const int b   = blk >> 2;
  const int n0  = (blk & 3) * 1024 + tid * 4;

  // ---- (a) global mean from the 1024 block totals ----
  float4 bs = bsum4[tid];              // 256 threads x 4 = 1024 entries
  uint4  bc = bcnt4[tid];
  float rs = bs.x + bs.y + bs.z + bs.w;
  unsigned int rc = bc.x + bc.y + bc.z + bc.w;
  for (int off = 32; off > 0; off >>= 1) {
    rs += __shfl_down(rs, off);
    rc += __shfl_down(rc, off);
  }
  __shared__ float sh_s[4];
  __shared__ unsigned int sh_c[4];
  __shared__ float sh_gmean;
  const int wid = tid >> 6;
  if ((tid & 63) == 0) { sh_s[wid] = rs; sh_c[wid] = rc; }
  __syncthreads();
  if (tid == 0) {
    float gs = sh_s[0] + sh_s[1] + sh_s[2] + sh_s[3];
    float gc = (float)(sh_c[0] + sh_c[1] + sh_c[2] + sh_c[3]);
    sh_gmean = gs / fmaxf(gc, 1.0f);
  }
  __syncthreads();
  const float gmean = sh_gmean;

  // ---- (b) combine packed partials {s0,c0,s1,c1}, impute, tile ----
  float4 s = make_float4(0.f, 0.f, 0.f, 0.f);   // sums for n0..n0+3
  float4 c = make_float4(0.f, 0.f, 0.f, 0.f);   // counts (exact fp32)
#pragma unroll
  for (int tc = 0; tc < TC; ++tc) {
    const size_t o2 = (((size_t)tc * BB + b) * NN + n0) / 2;
    float4 p0 = ps4[o2];       // {s(n0), c(n0), s(n0+1), c(n0+1)}
    float4 p1 = ps4[o2 + 1];   // {s(n0+2), c(n0+2), s(n0+3), c(n0+3)}
    s.x += p0.x; c.x += p0.y; s.y += p0.z; c.y += p0.w;
    s.z += p1.x; c.z += p1.y; s.w += p1.z; c.w += p1.w;
  }
  const float inv_t = 1.0f / (float)TT;
  float4 pred;
  pred.x = (s.x + ((float)TT - c.x) * gmean) * inv_t;
  pred.y = (s.y + ((float)TT - c.y) * gmean) * inv_t;
  pred.z = (s.z + ((float)TT - c.z) * gmean) * inv_t;
  pred.w = (s.w + ((float)TT - c.w) * gmean) * inv_t;

#pragma unroll
  for (int h = 0; h < HH; ++h)
    out4[((size_t)(b * HH + h) * NN + n0) / 4] = pred;

  // ---- (c) per-block regional sums -> device-scope accumulators ----
  __shared__ float rsh[RR];
  if (tid < RR) rsh[tid] = 0.0f;
  __syncthreads();
  int4 cl = cluster4[n0 / 4];
  atomicAdd(&rsh[cl.x], pred.x);
  atomicAdd(&rsh[cl.y], pred.y);
  atomicAdd(&rsh[cl.z], pred.z);
  atomicAdd(&rsh[cl.w], pred.w);
  __syncthreads();
  if (tid < RR) atomicAdd(&regsum[b * RR + tid], rsh[tid]);

  // ---- (d) last-block finalization (fused old k_final) ----
  __shared__ int sh_last;
  __threadfence();                       // release regsum adds
  if (tid == 0) {
    unsigned int old = atomicAdd(counter, 1u);
    sh_last = (old == NBLK2 - 1) ? 1 : 0;
  }
  __syncthreads();
  if (sh_last) {
    __threadfence();                     // acquire other blocks' adds
    __shared__ unsigned int hist[RR];
    if (tid < RR) hist[tid] = 0u;
    __syncthreads();
    for (int i = tid; i < NN; i += 256) atomicAdd(&hist[cluster[i]], 1u);
    __syncthreads();
    const int ob = tid >> 4;
    const int r  = tid & 15;
    // atomicAdd(+0) forces an L2-coherent read of the accumulated value
    const float sreg = atomicAdd(&regsum[tid], 0.0f);
    const float v = sreg / fmaxf((float)hist[r], 1.0f);
#pragma unroll
    for (int h = 0; h < HH; ++h)
      out2[(size_t)(ob * HH + h) * RR + r] = v;
  }
}

extern "C" void kernel_launch(void* const* d_in, const int* in_sizes, int n_in,
                              void* d_out, int out_size, void* d_ws, size_t ws_size,
                              hipStream_t stream) {
  const float* x       = (const float*)d_in[0];  // [B,T,N,F] fp32
  const int*   cluster = (const int*)d_in[1];    // [N] int32
  float* out = (float*)d_out;                    // [B,H,N] then [B,H,R]

  // Workspace layout (all slots written before read each call; the atomic
  // region {regsum, counter} is zero-initialized by k_partial each call):
  //   @0      ps     float4[TC*BB*NN/2]  (4 MB packed {s,c,s,c})
  //   @4MB    bsum   float[1024]
  //   @4MB+4K bcnt   uint[1024]
  //   @4MB+8K regsum float[BB*RR=256]
  //   @4MB+12K counter uint[1]
  float*        ps      = (float*)d_ws;
  float*        bsum    = (float*)((char*)d_ws + (size_t)TC * BB * NN * 8);
  unsigned int* bcnt    = (unsigned int*)((char*)bsum + 4096);
  float*        regsum  = (float*)((char*)bsum + 8192);
  unsigned int* counter = (unsigned int*)((char*)bsum + 12288);

  dim3 g1(NN / 512, TC, BB);
  k_partial<<<g1, 256, 0, stream>>>((const float4*)x, (float4*)ps,
                                    bsum, bcnt, regsum, counter);

  k_pred<<<NBLK2, 256, 0, stream>>>((const float4*)ps,
                                    (const float4*)bsum, (const uint4*)bcnt,
                                    (const int4*)cluster, cluster,
                                    (float4*)out, out + (size_t)BB * HH * NN,
                                    regsum, counter);
}